// Round 8
// baseline (206.706 us; speedup 1.0000x reference)
//
#include <hip/hip_runtime.h>

// B=16, T=512, D=384, target_len=4096. x: f32, durations: int32 (sniffed
// f32/i64/i32/i16 for safety), out: f32.
// Root-cause history: rounds 2-7 all had a 9-iteration binary search over
// [0,512] — searchsorted needs ceil(log2(513)) = 10 iterations. Fixed here.
#define B_   16
#define T_   512
#define TLEN 4096
#define XC   96   // 16B f32 chunks per row (384*4/16)
#define RPB  4    // output rows per block (384 threads / 96 lanes)

typedef float f4v __attribute__((ext_vector_type(4)));

__global__ __launch_bounds__(384) void lr_fused(const f4v* __restrict__ x,
                                                const unsigned int* __restrict__ durw,
                                                f4v* __restrict__ out) {
    __shared__ int sd[T_];      // max(dur,1)
    __shared__ int sp[T_ / 2];  // pair partials (scanned)
    __shared__ int sc[T_];      // inclusive cumsum

    const int tid  = threadIdx.x;
    const int row0 = blockIdx.x * RPB;   // 4096 % 4 == 0: no batch straddle
    const int b    = row0 >> 12;

    // ---- durations dtype sniff (deterministic, wave-uniform; values 0..15).
    int f32ok = 1, i64ok = 1, i32ok = 1, i16ok = 1;
    #pragma unroll
    for (int k = 0; k < 32; ++k) {
        unsigned w = durw[k];
        f32ok &= (int)((w == 0u) | ((w >= 0x3F800000u) & (w <= 0x41700000u)));
        i64ok &= (int)((k & 1) ? (w == 0u) : (w <= 15u));
        i32ok &= (int)(w <= 15u);
        i16ok &= (int)(((w & 0xFFFFu) <= 15u) & ((w >> 16) <= 15u));
    }

    // ---- per-batch inclusive cumsum of max(dur,1) in LDS ----
    for (int i = tid; i < T_; i += 384) {
        const int e = b * T_ + i;
        int v;
        if (f32ok)      v = (int)__uint_as_float(durw[e]);
        else if (i64ok) v = (int)durw[e * 2];                       // LE low word
        else if (i32ok) v = (int)durw[e];
        else if (i16ok) v = (int)((durw[e >> 1] >> (16 * (e & 1))) & 0xFFFFu);
        else            v = (int)durw[e];                           // fallback i32
        sd[i] = v < 1 ? 1 : v;
    }
    __syncthreads();
    if (tid < 256) sp[tid] = sd[2 * tid] + sd[2 * tid + 1];
    __syncthreads();
    for (int off = 1; off < 256; off <<= 1) {
        int add = (tid < 256 && tid >= off) ? sp[tid - off] : 0;
        __syncthreads();
        if (tid < 256) sp[tid] += add;
        __syncthreads();
    }
    if (tid < 256) {
        int P = sp[tid];                 // inclusive sum through elem 2tid+1
        sc[2 * tid + 1] = P;
        sc[2 * tid]     = P - sd[2 * tid + 1];
    }
    __syncthreads();

    const int total = sc[T_ - 1];
    const int sub = tid / XC;            // 0..3
    const int col = tid - sub * XC;      // 0..95
    const int row = row0 + sub;
    const int t   = row & (TLEN - 1);

    f4v val = (f4v){0.f, 0.f, 0.f, 0.f};
    if (t < total) {
        // searchsorted side='right': first i with sc[i] > t.
        // 10 iterations (513 possible outcomes). Within this guard the
        // answer <= 511, so convergence is stable and sc[512] is never read.
        int lo = 0, hi = T_;
        #pragma unroll
        for (int i = 0; i < 10; ++i) {
            int mid = (lo + hi) >> 1;
            if (sc[mid] > t) hi = mid; else lo = mid + 1;
        }
        const int idx = lo > (T_ - 1) ? (T_ - 1) : lo;
        val = x[(b * T_ + idx) * XC + col];
    }
    // Write-once 100MB output stream: nontemporal keeps L2 for the x gather.
    __builtin_nontemporal_store(val, &out[(size_t)row * XC + col]);
}

extern "C" void kernel_launch(void* const* d_in, const int* in_sizes, int n_in,
                              void* d_out, int out_size, void* d_ws, size_t ws_size,
                              hipStream_t stream) {
    // d_in[0]=x, d_in[1]=durations, d_in[2]=target_len (shapes fixed).
    lr_fused<<<(B_ * TLEN) / RPB, 384, 0, stream>>>(
        (const f4v*)d_in[0], (const unsigned int*)d_in[1], (f4v*)d_out);
}

// Round 9
// 134.022 us; speedup vs baseline: 1.5423x; 1.5423x over previous
//
#include <hip/hip_runtime.h>

// B=16, T=512, D=384, target_len=4096. x: f32, durations: int32 (sniffed
// f32/i64/i32/i16), out: f32. Two kernels: per-batch scan once (16 blocks),
// then a pure streaming expand (2048 blocks x 32 rows) — R8's fused version
// recomputed the 512-elem scan in every one of 16384 blocks (19 barriers per
// 6 KB of output) and sat at 11% of HBM peak.
#define B_   16
#define T_   512
#define TLEN 4096
#define XC   96    // 16B f32 chunks per row (384*4/16)
#define RPB  32    // output rows per expand block
#define NP   8     // passes: RPB / (384/96)

typedef float f4v __attribute__((ext_vector_type(4)));

// Kernel 1: per-batch inclusive cumsum of max(dur,1) -> cum in workspace.
__global__ __launch_bounds__(T_) void lr_scan(const unsigned int* __restrict__ durw,
                                              int* __restrict__ cum) {
    __shared__ int s[T_];
    const int b = blockIdx.x;
    const int t = threadIdx.x;

    // durations dtype sniff (deterministic, wave-uniform; values 0..15)
    int f32ok = 1, i64ok = 1, i32ok = 1, i16ok = 1;
    #pragma unroll
    for (int k = 0; k < 32; ++k) {
        unsigned w = durw[k];
        f32ok &= (int)((w == 0u) | ((w >= 0x3F800000u) & (w <= 0x41700000u)));
        i64ok &= (int)((k & 1) ? (w == 0u) : (w <= 15u));
        i32ok &= (int)(w <= 15u);
        i16ok &= (int)(((w & 0xFFFFu) <= 15u) & ((w >> 16) <= 15u));
    }

    const int e = b * T_ + t;
    int v;
    if (f32ok)      v = (int)__uint_as_float(durw[e]);
    else if (i64ok) v = (int)durw[e * 2];                       // LE low word
    else if (i32ok) v = (int)durw[e];
    else if (i16ok) v = (int)((durw[e >> 1] >> (16 * (e & 1))) & 0xFFFFu);
    else            v = (int)durw[e];
    s[t] = v < 1 ? 1 : v;
    __syncthreads();
    for (int off = 1; off < T_; off <<= 1) {
        int add = (t >= off) ? s[t - off] : 0;
        __syncthreads();
        s[t] += add;
        __syncthreads();
    }
    cum[b * T_ + t] = s[t];
}

// Kernel 2: expansion. 2048 blocks x 384 threads; each block serves 32 rows
// of one batch (4096 % 32 == 0: no straddle). Load cum row to LDS once, then
// 8 unrolled independent search+gather+store passes (96 lanes per row, 16 B
// per lane). Searches are broadcast/2-way LDS reads (free); ILP across the
// 8 passes + 6 waves/block hides LDS and L2 latency.
__global__ __launch_bounds__(384) void lr_expand(const f4v* __restrict__ x,
                                                 const int* __restrict__ cum,
                                                 f4v* __restrict__ out) {
    __shared__ int sc[T_];
    const int tid  = threadIdx.x;
    const int row0 = blockIdx.x * RPB;
    const int b    = row0 >> 12;

    for (int i = tid; i < T_; i += 384) sc[i] = cum[b * T_ + i];
    __syncthreads();

    const int total = sc[T_ - 1];
    const int sub = tid / XC;              // 0..3
    const int col = tid - sub * XC;        // 0..95

    #pragma unroll
    for (int p = 0; p < NP; ++p) {
        const int row = row0 + p * 4 + sub;
        const int t   = row & (TLEN - 1);
        f4v val = (f4v){0.f, 0.f, 0.f, 0.f};
        if (t < total) {
            // searchsorted side='right': first i with sc[i] > t.
            // 10 iterations: 513 outcomes need ceil(log2(513)) = 10.
            int lo = 0, hi = T_;
            #pragma unroll
            for (int i = 0; i < 10; ++i) {
                int mid = (lo + hi) >> 1;
                if (sc[mid] > t) hi = mid; else lo = mid + 1;
            }
            const int idx = lo > (T_ - 1) ? (T_ - 1) : lo;
            val = x[(b * T_ + idx) * XC + col];
        }
        // Write-once 100MB stream: nontemporal keeps L2 for the x gather.
        __builtin_nontemporal_store(val, &out[(size_t)row * XC + col]);
    }
}

extern "C" void kernel_launch(void* const* d_in, const int* in_sizes, int n_in,
                              void* d_out, int out_size, void* d_ws, size_t ws_size,
                              hipStream_t stream) {
    // d_in[0]=x, d_in[1]=durations, d_in[2]=target_len (shapes fixed).
    int* cum = (int*)d_ws;   // 16*512 i32 = 32 KB scratch
    lr_scan<<<B_, T_, 0, stream>>>((const unsigned int*)d_in[1], cum);
    lr_expand<<<(B_ * TLEN) / RPB, 384, 0, stream>>>(
        (const f4v*)d_in[0], cum, (f4v*)d_out);
}

// Round 10
// 128.693 us; speedup vs baseline: 1.6062x; 1.0414x over previous
//
#include <hip/hip_runtime.h>

// B=16, T=512, D=384, target_len=4096. x: f32, durations: int32 (sniffed
// f32/i64/i32/i16), out: f32.
// R9 post-mortem: expand ~60us at 1.9 TB/s, limited by redundant per-thread
// binary searches (8 x 10-step dependent LDS chains). Fix: build an explicit
// u16 token-index map once (16 blocks, scatter-inverse of searchsorted),
// then a search-free gather-stream kernel (same shape as the 6.4 TB/s
// harness fill kernel).
#define B_   16
#define T_   512
#define TLEN 4096
#define XC   96    // 16B f32 chunks per row (384*4/16)
#define RPB  8     // rows per expand block (384 threads / 96 lanes * 2 passes)
#define SENT 0xFFFFu

typedef float f4v __attribute__((ext_vector_type(4)));

__device__ __forceinline__ int sniff_dur(const unsigned int* __restrict__ durw,
                                         int e) {
    // dtype sniff on first 32 words (deterministic, uniform; values 0..15)
    int f32ok = 1, i64ok = 1, i32ok = 1, i16ok = 1;
    #pragma unroll
    for (int k = 0; k < 32; ++k) {
        unsigned w = durw[k];
        f32ok &= (int)((w == 0u) | ((w >= 0x3F800000u) & (w <= 0x41700000u)));
        i64ok &= (int)((k & 1) ? (w == 0u) : (w <= 15u));
        i32ok &= (int)(w <= 15u);
        i16ok &= (int)(((w & 0xFFFFu) <= 15u) & ((w >> 16) <= 15u));
    }
    int v;
    if (f32ok)      v = (int)__uint_as_float(durw[e]);
    else if (i64ok) v = (int)durw[e * 2];
    else if (i32ok) v = (int)durw[e];
    else if (i16ok) v = (int)((durw[e >> 1] >> (16 * (e & 1))) & 0xFFFFu);
    else            v = (int)durw[e];
    return v;
}

// Kernel 1a: per-batch scan + scatter-inverse -> idx map (u16, 0xFFFF = pad).
// One block per batch, 512 threads.
__global__ __launch_bounds__(T_) void lr_build_idx(const unsigned int* __restrict__ durw,
                                                   unsigned short* __restrict__ idx) {
    __shared__ int s[T_];
    const int b = blockIdx.x;
    const int t = threadIdx.x;

    int v = sniff_dur(durw, b * T_ + t);
    s[t] = v < 1 ? 1 : v;
    __syncthreads();
    for (int off = 1; off < T_; off <<= 1) {
        int add = (t >= off) ? s[t - off] : 0;
        __syncthreads();
        s[t] += add;
        __syncthreads();
    }
    const int cum  = s[t];
    const int prev = t ? s[t - 1] : 0;   // safe: loop ended with a barrier

    // init row to sentinel (entries >= total stay sentinel)
    unsigned short* row = idx + b * TLEN;
    for (int i = t; i < TLEN; i += T_) row[i] = (unsigned short)SENT;
    __syncthreads();

    // token t covers output positions [prev, cum) clamped to TLEN
    const int end = cum < TLEN ? cum : TLEN;
    for (int j = prev; j < end; ++j) row[j] = (unsigned short)t;
}

// Kernel 2a: search-free gather-stream. 8192 blocks x 384 threads; each
// thread: one broadcast u16 idx load, one 16B L2-hot x load, one 16B NT store.
__global__ __launch_bounds__(384) void lr_expand_idx(const f4v* __restrict__ x,
                                                     const unsigned short* __restrict__ idx,
                                                     f4v* __restrict__ out) {
    const int tid = threadIdx.x;
    const int sub = tid / XC;              // 0..3
    const int col = tid - sub * XC;        // 0..95
    const int row0 = blockIdx.x * RPB;
    const int b = row0 >> 12;              // 4096 rows per batch

    #pragma unroll
    for (int p = 0; p < 2; ++p) {
        const int row = row0 + p * 4 + sub;
        const unsigned iv = idx[row];      // same addr across 96 lanes: L1 broadcast
        f4v val = (f4v){0.f, 0.f, 0.f, 0.f};
        if (iv != SENT) val = x[(b * T_ + (int)iv) * XC + col];
        __builtin_nontemporal_store(val, &out[(size_t)row * XC + col]);
    }
}

// ---- Fallback (ws too small for the idx map): R9's cum + binary search ----
__global__ __launch_bounds__(T_) void lr_scan(const unsigned int* __restrict__ durw,
                                              int* __restrict__ cum) {
    __shared__ int s[T_];
    const int b = blockIdx.x;
    const int t = threadIdx.x;
    int v = sniff_dur(durw, b * T_ + t);
    s[t] = v < 1 ? 1 : v;
    __syncthreads();
    for (int off = 1; off < T_; off <<= 1) {
        int add = (t >= off) ? s[t - off] : 0;
        __syncthreads();
        s[t] += add;
        __syncthreads();
    }
    cum[b * T_ + t] = s[t];
}

__global__ __launch_bounds__(384) void lr_expand(const f4v* __restrict__ x,
                                                 const int* __restrict__ cum,
                                                 f4v* __restrict__ out) {
    __shared__ int sc[T_];
    const int tid  = threadIdx.x;
    const int row0 = blockIdx.x * 32;
    const int b    = row0 >> 12;
    for (int i = tid; i < T_; i += 384) sc[i] = cum[b * T_ + i];
    __syncthreads();
    const int total = sc[T_ - 1];
    const int sub = tid / XC;
    const int col = tid - sub * XC;
    #pragma unroll
    for (int p = 0; p < 8; ++p) {
        const int row = row0 + p * 4 + sub;
        const int t   = row & (TLEN - 1);
        f4v val = (f4v){0.f, 0.f, 0.f, 0.f};
        if (t < total) {
            int lo = 0, hi = T_;
            #pragma unroll
            for (int i = 0; i < 10; ++i) {   // 513 outcomes -> 10 iters
                int mid = (lo + hi) >> 1;
                if (sc[mid] > t) hi = mid; else lo = mid + 1;
            }
            const int idx2 = lo > (T_ - 1) ? (T_ - 1) : lo;
            val = x[(b * T_ + idx2) * XC + col];
        }
        __builtin_nontemporal_store(val, &out[(size_t)row * XC + col]);
    }
}

extern "C" void kernel_launch(void* const* d_in, const int* in_sizes, int n_in,
                              void* d_out, int out_size, void* d_ws, size_t ws_size,
                              hipStream_t stream) {
    // d_in[0]=x, d_in[1]=durations, d_in[2]=target_len (shapes fixed).
    const f4v* x = (const f4v*)d_in[0];
    const unsigned int* durw = (const unsigned int*)d_in[1];

    if (ws_size >= (size_t)(B_ * TLEN * 2)) {         // 128 KB idx map
        unsigned short* idx = (unsigned short*)d_ws;
        lr_build_idx<<<B_, T_, 0, stream>>>(durw, idx);
        lr_expand_idx<<<(B_ * TLEN) / RPB, 384, 0, stream>>>(x, idx, (f4v*)d_out);
    } else {                                          // 32 KB cum fallback
        int* cum = (int*)d_ws;
        lr_scan<<<B_, T_, 0, stream>>>(durw, cum);
        lr_expand<<<(B_ * TLEN) / 32, 384, 0, stream>>>(x, cum, (f4v*)d_out);
    }
}